// Round 7
// baseline (521.711 us; speedup 1.0000x reference)
//
#include <hip/hip_runtime.h>

// SpikingNN LIF scan: N=131072 traces x L=401 steps, fp32. Bit-exact vs ref.
//
// Round-7: R6 (178us) + three fixes.
//  R6 post-mortem: 64 cyc/VMEM-instr (427k cyc / 6656 instrs per CU) with
//  depth-1 prefetch = per-chunk latency exposure (gll issued ~400cy before
//  its wait vs 900-1800cy HBM latency). Fixes:
//   1) depth-2 pipeline: 3 buffers/wave, issue gll_{c+2} each iter -> the
//      vmcnt wait targets loads issued ~2 iterations earlier. Counted
//      ledger (loads 32/chunk, stores 8/chunk): vmcnt 32 / 40 / 48 / 16.
//   2) stores as global_store_dwordx4: gather 4 swizzled dwords from LDS
//      (~2-way conflict = free) -> 8 store instrs/chunk (was 32).
//   3) 128-thread blocks (2 waves) x 1024: LDS 48KB -> 3 blocks/CU,
//      6 waves/CU, ~16KB loads in flight per wave steady-state.
//  Wave-private everything, ZERO barriers (same-wave ordering + vmcnt only).
//  LDS swizzle (R6-proven, conflicts=0): physical slot o of row r holds
//  logical col o^(r&31); gll source pre-swizzled (m173), dest linear.
//  Scan math in exact ref op order; i==0 folded via P=0,t_rest=-1.

#define L_STEPS 401
#define NCHUNK  13
#define CHUNK   32
#define BLKT    128                    // 2 waves per block
#define NWAVES  (BLKT / 64)
#define SLICE   (64 * CHUNK)           // 2048 dwords = 8 KB per buffer

typedef const __attribute__((address_space(1))) void* gas1_t;
typedef __attribute__((address_space(3))) void*       las3_t;
typedef float f4v __attribute__((ext_vector_type(4), aligned(4)));

__global__ __launch_bounds__(BLKT) void snn_scan_kernel(
    const float* __restrict__ S, float* __restrict__ out)
{
    __shared__ float smem[NWAVES][3][SLICE];   // 48 KB -> 3 blocks/CU

    const int tid       = threadIdx.x;
    const int wave      = tid >> 6;
    const int lane      = tid & 63;
    const int traceBase = blockIdx.x * BLKT + wave * 64;

    float P = 0.0f, t_rest = -1.0f;            // folds the i==0 branch

    // 32 x gll(width4) for the chunk at column ccol into buffer b.
    // LDS dest linear (slot k*64 + lane); global source pre-swizzled so
    // slot s holds (row = s>>5, col = (s&31) ^ (row&31)).
    auto stage = [&](int ccol, int b) {
        #pragma unroll
        for (int k = 0; k < 32; ++k) {
            const int s_  = k * 64 + lane;
            const int row = s_ >> 5;
            const int col = (s_ & 31) ^ (row & 31);
            int gc = ccol + col;
            if (gc > 400) gc = 400;            // tail clamp (dup, never stored)
            const float* gp = S + (size_t)(traceBase + row) * L_STEPS + gc;
            __builtin_amdgcn_global_load_lds(
                (gas1_t)gp, (las3_t)&smem[wave][b][k * 64], 4, 0, 0);
        }
    };

    stage(0,     0);                           // depth-2 prologue
    stage(CHUNK, 1);

    #pragma unroll 1
    for (int c = 0; c < NCHUNK; ++c) {
        const int c0 = c * CHUNK;
        const int b  = c % 3;

        // Wait for gll_c. In-issue-order outstanding queues:
        //  c=0:  [g0 32][g1 32]                  -> vmcnt(32)
        //  c=1:  [g1 32][g2 32][s0 8]            -> vmcnt(40)
        //  2<=c<=11: [gc 32][s(c-2) 8][g(c+1) 32][s(c-1) 8] -> vmcnt(48)
        //  c=12: [g12 32][s10 8][s11 8]          -> vmcnt(16)
        if (c == 0)              asm volatile("s_waitcnt vmcnt(32)" ::: "memory");
        else if (c == 1)         asm volatile("s_waitcnt vmcnt(40)" ::: "memory");
        else if (c < NCHUNK - 1) asm volatile("s_waitcnt vmcnt(48)" ::: "memory");
        else                     asm volatile("s_waitcnt vmcnt(16)" ::: "memory");

        // ---- read own row (swizzled, 2-way = free) ----
        float sv[CHUNK];
        #pragma unroll
        for (int j = 0; j < CHUNK; ++j)
            sv[j] = smem[wave][b][lane * CHUNK + (j ^ (lane & 31))];

        // ---- LIF scan, exact ref op order (tail runs harmless dup steps) ----
        #pragma unroll
        for (int j = 0; j < CHUNK; ++j) {
            const float t = (float)(c0 + j) * 0.125f;          // exact in fp32
            float p = (t <= t_rest)
                    ? 0.0f
                    : ((P > -1.0f) ? (P + sv[j]) - 0.25f : 0.0f);
            const bool spike = (p >= 25.0f);
            t_rest = spike ? t + 5.0f : t_rest;                // exact in fp32
            p      = spike ? p + 4.0f : p;
            sv[j]  = p;
            P      = p;
        }

        // ---- write back (same swizzle) ----
        #pragma unroll
        for (int j = 0; j < CHUNK; ++j)
            smem[wave][b][lane * CHUNK + (j ^ (lane & 31))] = sv[j];

        asm volatile("" ::: "memory");

        // ---- issue stage(c+2): buffer (c+2)%3 == (c-1)%3, freed last iter ----
        if (c + 2 < NCHUNK) stage(c0 + 2 * CHUNK, (c + 2) % 3);
        asm volatile("" ::: "memory");

        // ---- store chunk c: 8 instrs of dwordx4 (gather 4 swizzled dwords) ----
        {
            const int q  = lane & 7;           // col-quad 0..7
            const int rb = lane >> 3;          // row offset 0..7
            #pragma unroll
            for (int k = 0; k < 8; ++k) {
                const int r  = 8 * k + rb;
                const int rx = r & 31;
                const float v0 = smem[wave][b][r * CHUNK + ((4 * q + 0) ^ rx)];
                const float v1 = smem[wave][b][r * CHUNK + ((4 * q + 1) ^ rx)];
                const float v2 = smem[wave][b][r * CHUNK + ((4 * q + 2) ^ rx)];
                const float v3 = smem[wave][b][r * CHUNK + ((4 * q + 3) ^ rx)];
                const int gc = c0 + 4 * q;
                float* op = out + (size_t)(traceBase + r) * L_STEPS + gc;
                if (gc + 3 <= 400) {                    // full quad (all c<12)
                    f4v v = {v0, v1, v2, v3};
                    *(f4v*)op = v;
                } else if (gc <= 400) {                 // tail: col 400 only
                    op[0] = v0;
                    if (gc + 1 <= 400) op[1] = v1;
                    if (gc + 2 <= 400) op[2] = v2;
                }
            }
        }
        asm volatile("" ::: "memory");
    }
}

extern "C" void kernel_launch(void* const* d_in, const int* in_sizes, int n_in,
                              void* d_out, int out_size, void* d_ws, size_t ws_size,
                              hipStream_t stream)
{
    // d_in[0] = Pn (dead in reference), d_in[1] = S
    const float* S   = (const float*)d_in[1];
    float*       out = (float*)d_out;

    snn_scan_kernel<<<(131072 / BLKT), BLKT, 0, stream>>>(S, out);
}